// Round 10
// baseline (339.727 us; speedup 1.0000x reference)
//
#include <hip/hip_runtime.h>

#define N_NODESC 100000
#define N_EDGESC 1600000
#define HCC 128                      // HEADS*OUT_CH
#define E_TOTC (N_EDGESC + N_NODESC) // edges + self loops (divisible by 4)
#define SCAN_NB 391                  // ceil(N_NODES/256)
#define PROJ_NB 782                  // ceil(N_NODES/128)
#define QUAD_NB 1661                 // ceil(E_TOT/4/256)

#define FLAG_AGG 0x40000000u
#define FLAG_PRE 0x80000000u
#define VAL_MASK 0x3fffffffu

__device__ __forceinline__ float lrelu(float v) { return fmaxf(v, 0.2f * v); }
__device__ __forceinline__ unsigned short f2bf(float f) {   // RNE bf16
    unsigned u = __float_as_uint(f);
    unsigned r = ((u >> 16) & 1u) + 0x7fffu;
    return (unsigned short)((u + r) >> 16);
}

// ---- CSR pos pass: 4 edges/thread, int4 loads ----
__global__ void pos_kernel(const int* __restrict__ ei, int* __restrict__ deg,
                           int* __restrict__ posb) {
    const int q = blockIdx.x * 256 + threadIdx.x;
    const int e0 = q * 4;
    if (e0 >= E_TOTC) return;
    int d[4];
    if (e0 + 3 < N_EDGESC) {
        int4 dd = *(const int4*)&ei[N_EDGESC + e0];
        d[0] = dd.x; d[1] = dd.y; d[2] = dd.z; d[3] = dd.w;
    } else {
#pragma unroll
        for (int j = 0; j < 4; ++j) {
            int e = e0 + j;
            d[j] = (e < N_EDGESC) ? ei[N_EDGESC + e] : (e - N_EDGESC);
        }
    }
    int p[4];
#pragma unroll
    for (int j = 0; j < 4; ++j) p[j] = atomicAdd(&deg[d[j]], 1);
    *(int4*)&posb[e0] = make_int4(p[0], p[1], p[2], p[3]);
}

// ---- augmented projection GEMM: [N x 64] @ [64 x (128 h + 16 a)] ----
// W-transpose and U = W_h^T att staged per-block (L2-hot, one-time cost).
__launch_bounds__(256, 2)
__global__ void proj_kernel(const float* __restrict__ x, const float* __restrict__ W,
                            const float* __restrict__ att_src, const float* __restrict__ att_dst,
                            unsigned short* __restrict__ h16,
                            float* __restrict__ a_src, float* __restrict__ a_dst) {
    __shared__ float xs[128][68];
    __shared__ float ws[64][132];
    __shared__ float us[64][16];
    const int t = threadIdx.x;
    const int row0 = blockIdx.x * 128;

    // stage x tile (issue global loads first)
    float4 xv4[8];
#pragma unroll
    for (int j = 0; j < 8; ++j) {
        int f = (t + 256 * j) * 4;
        int gr = row0 + (f >> 6);
        if (gr >= N_NODESC) gr = N_NODESC - 1;
        xv4[j] = *(const float4*)&x[(size_t)gr * 64 + (f & 63)];
    }
    // transpose W [128][64] -> ws[k][c]
    const float4* W4 = (const float4*)W;    // 2048 float4
#pragma unroll
    for (int j = 0; j < 8; ++j) {
        int q = t + 256 * j;
        float4 v = W4[q];
        int c = q >> 4, k0 = (q & 15) * 4;
        ws[k0 + 0][c] = v.x; ws[k0 + 1][c] = v.y;
        ws[k0 + 2][c] = v.z; ws[k0 + 3][c] = v.w;
    }
    // U: us[k][c] = sum_j av[h*16+j] * W[(h*16+j)*64+k]
#pragma unroll
    for (int j = 0; j < 4; ++j) {
        int o = t + 256 * j;
        int k = o >> 4, c = o & 15;
        const int h = c & 7;
        const float* av = (c < 8) ? att_src : att_dst;
        float s = 0.f;
#pragma unroll
        for (int jj = 0; jj < 16; ++jj) s += av[h * 16 + jj] * W[(h * 16 + jj) * 64 + k];
        us[k][c] = s;
    }
#pragma unroll
    for (int j = 0; j < 8; ++j) {
        int f = (t + 256 * j) * 4;
        *(float4*)&xs[f >> 6][f & 63] = xv4[j];
    }
    __syncthreads();

    const int rg = t & 15;
    const int cg = t >> 4;
    float acc[8][8], acca[8];
#pragma unroll
    for (int i = 0; i < 8; ++i) {
        acca[i] = 0.f;
#pragma unroll
        for (int j = 0; j < 8; ++j) acc[i][j] = 0.f;
    }

#pragma unroll 4
    for (int k = 0; k < 64; ++k) {
        float xv[8];
#pragma unroll
        for (int i = 0; i < 8; ++i) xv[i] = xs[rg + 16 * i][k];
        float4 w0 = *(const float4*)&ws[k][4 * cg];
        float4 w1 = *(const float4*)&ws[k][64 + 4 * cg];
        float uv = us[k][cg];
#pragma unroll
        for (int i = 0; i < 8; ++i) {
            acc[i][0] += xv[i] * w0.x; acc[i][1] += xv[i] * w0.y;
            acc[i][2] += xv[i] * w0.z; acc[i][3] += xv[i] * w0.w;
            acc[i][4] += xv[i] * w1.x; acc[i][5] += xv[i] * w1.y;
            acc[i][6] += xv[i] * w1.z; acc[i][7] += xv[i] * w1.w;
            acca[i]   += xv[i] * uv;
        }
    }

#pragma unroll
    for (int i = 0; i < 8; ++i) {
        int gr = row0 + rg + 16 * i;
        if (gr < N_NODESC) {
            ushort4 p0, p1;
            p0.x = f2bf(acc[i][0]); p0.y = f2bf(acc[i][1]); p0.z = f2bf(acc[i][2]); p0.w = f2bf(acc[i][3]);
            p1.x = f2bf(acc[i][4]); p1.y = f2bf(acc[i][5]); p1.z = f2bf(acc[i][6]); p1.w = f2bf(acc[i][7]);
            *(ushort4*)&h16[(size_t)gr * HCC + 4 * cg] = p0;
            *(ushort4*)&h16[(size_t)gr * HCC + 64 + 4 * cg] = p1;
            if (cg < 8) a_src[(size_t)gr * 8 + cg] = acca[i];
            else        a_dst[(size_t)gr * 8 + cg - 8] = acca[i];
        }
    }
}

// ---- single-kernel exclusive scan (decoupled lookback) -> rowptr ----
__global__ void scan_kernel(const int* __restrict__ deg, unsigned* __restrict__ state,
                            int* __restrict__ rowptr) {
    __shared__ int lds[256];
    __shared__ int s_prefix;
    const int b = blockIdx.x, t = threadIdx.x;
    const int i = b * 256 + t;
    const int v = (i < N_NODESC) ? deg[i] : 0;
    lds[t] = v;
    __syncthreads();
    for (int off = 1; off < 256; off <<= 1) {
        int u = 0;
        if (t >= off) u = lds[t - off];
        __syncthreads();
        if (t >= off) lds[t] += u;
        __syncthreads();
    }
    const int incl = lds[t];
    const int total = lds[255];
    if (t == 0) {
        if (b == 0) {
            atomicExch(&state[0], FLAG_PRE | (unsigned)total);
            s_prefix = 0;
        } else {
            atomicExch(&state[b], FLAG_AGG | (unsigned)total);
            unsigned run = 0;
            int j = b - 1;
            while (true) {
                unsigned s = atomicAdd(&state[j], 0u);
                if (s & FLAG_PRE) { run += s & VAL_MASK; break; }
                if (s & FLAG_AGG) { run += s & VAL_MASK; --j; }
            }
            atomicExch(&state[b], FLAG_PRE | ((unsigned)total + run));
            s_prefix = (int)run;
        }
    }
    __syncthreads();
    const int excl = s_prefix + incl - v;
    if (i <= N_NODESC) rowptr[i] = excl;   // i==N writes rowptr[N] = E_TOT
}

// ---- scatter: 4 edges/thread, int4 loads, no atomics ----
__global__ void scatter_kernel(const int* __restrict__ ei, const int* __restrict__ rowptr,
                               const int* __restrict__ posb, int* __restrict__ colsrc) {
    const int q = blockIdx.x * 256 + threadIdx.x;
    const int e0 = q * 4;
    if (e0 >= E_TOTC) return;
    int4 pp = *(const int4*)&posb[e0];
    int s[4], d[4], p[4] = { pp.x, pp.y, pp.z, pp.w };
    if (e0 + 3 < N_EDGESC) {
        int4 ss = *(const int4*)&ei[e0];
        int4 dd = *(const int4*)&ei[N_EDGESC + e0];
        s[0] = ss.x; s[1] = ss.y; s[2] = ss.z; s[3] = ss.w;
        d[0] = dd.x; d[1] = dd.y; d[2] = dd.z; d[3] = dd.w;
    } else {
#pragma unroll
        for (int j = 0; j < 4; ++j) {
            int e = e0 + j;
            if (e < N_EDGESC) { s[j] = ei[e]; d[j] = ei[N_EDGESC + e]; }
            else              { s[j] = d[j] = e - N_EDGESC; }
        }
    }
    int r[4];
#pragma unroll
    for (int j = 0; j < 4; ++j) r[j] = rowptr[d[j]];
#pragma unroll
    for (int j = 0; j < 4; ++j) colsrc[r[j] + p[j]] = s[j];
}

// ---- gather aggregation: 16 edges/iter (2 streams/lane), 2-deep pipeline ----
// One wave per node. Lane L = (head hd=L>>3, e-slot eL=L&7) owns edges
// p0+eL (stream A) and p0+8+eL (stream B). Per iter: 4x uint4 h-loads +
// 2 colsrc + 2 a_src, all independent of each other.
__launch_bounds__(256, 8)
__global__ void agg_csr_kernel(const int* __restrict__ rowptr, const int* __restrict__ colsrc,
                               const float* __restrict__ a_src, const float* __restrict__ a_dst,
                               const unsigned* __restrict__ h32,
                               const float* __restrict__ bias, float* __restrict__ out) {
    const int t = threadIdx.x;
    const int L = t & 63;
    const int n = blockIdx.x * 4 + (t >> 6);
    const int hd = L >> 3;
    const int eL = L & 7;

    const int beg = rowptr[n], end = rowptr[n + 1];
    const float ad = a_dst[n * 8 + hd];

    float den = 0.f;
    float acc[16];
#pragma unroll
    for (int j = 0; j < 16; ++j) acc[j] = 0.f;

    int pA = beg + eL;
    int pB = beg + 8 + eL;
    bool vA0 = pA < end,       vB0 = pB < end;
    bool vA1 = pA + 16 < end,  vB1 = pB + 16 < end;
    int sA0 = vA0 ? colsrc[pA] : 0;
    int sB0 = vB0 ? colsrc[pB] : 0;
    int sA1 = vA1 ? colsrc[pA + 16] : 0;
    int sB1 = vB1 ? colsrc[pB + 16] : 0;
    float aA0 = vA0 ? a_src[sA0 * 8 + hd] : 0.f;
    float aB0 = vB0 ? a_src[sB0 * 8 + hd] : 0.f;

    while (vA0) {
        // current iteration h loads (independent)
        const uint4* hpA = (const uint4*)(h32 + (size_t)sA0 * 64 + hd * 8);
        const uint4 ha0 = hpA[0], ha1 = hpA[1];
        const uint4* hpB = (const uint4*)(h32 + (size_t)sB0 * 64 + hd * 8);
        const uint4 hb0 = hpB[0], hb1 = hpB[1];
        // prefetch iter+2 colsrc, iter+1 a_src
        const bool vA2 = pA + 32 < end, vB2 = pB + 32 < end;
        const int sA2 = vA2 ? colsrc[pA + 32] : 0;
        const int sB2 = vB2 ? colsrc[pB + 32] : 0;
        const float aA1 = vA1 ? a_src[sA1 * 8 + hd] : 0.f;
        const float aB1 = vB1 ? a_src[sB1 * 8 + hd] : 0.f;

        const float prA = __expf(lrelu(aA0 + ad));
        const float prB = vB0 ? __expf(lrelu(aB0 + ad)) : 0.f;
        den += prA + prB;

        acc[0]  = fmaf(prA, __uint_as_float(ha0.x << 16),         acc[0]);
        acc[1]  = fmaf(prA, __uint_as_float(ha0.x & 0xffff0000u), acc[1]);
        acc[2]  = fmaf(prA, __uint_as_float(ha0.y << 16),         acc[2]);
        acc[3]  = fmaf(prA, __uint_as_float(ha0.y & 0xffff0000u), acc[3]);
        acc[4]  = fmaf(prA, __uint_as_float(ha0.z << 16),         acc[4]);
        acc[5]  = fmaf(prA, __uint_as_float(ha0.z & 0xffff0000u), acc[5]);
        acc[6]  = fmaf(prA, __uint_as_float(ha0.w << 16),         acc[6]);
        acc[7]  = fmaf(prA, __uint_as_float(ha0.w & 0xffff0000u), acc[7]);
        acc[8]  = fmaf(prA, __uint_as_float(ha1.x << 16),         acc[8]);
        acc[9]  = fmaf(prA, __uint_as_float(ha1.x & 0xffff0000u), acc[9]);
        acc[10] = fmaf(prA, __uint_as_float(ha1.y << 16),         acc[10]);
        acc[11] = fmaf(prA, __uint_as_float(ha1.y & 0xffff0000u), acc[11]);
        acc[12] = fmaf(prA, __uint_as_float(ha1.z << 16),         acc[12]);
        acc[13] = fmaf(prA, __uint_as_float(ha1.z & 0xffff0000u), acc[13]);
        acc[14] = fmaf(prA, __uint_as_float(ha1.w << 16),         acc[14]);
        acc[15] = fmaf(prA, __uint_as_float(ha1.w & 0xffff0000u), acc[15]);

        acc[0]  = fmaf(prB, __uint_as_float(hb0.x << 16),         acc[0]);
        acc[1]  = fmaf(prB, __uint_as_float(hb0.x & 0xffff0000u), acc[1]);
        acc[2]  = fmaf(prB, __uint_as_float(hb0.y << 16),         acc[2]);
        acc[3]  = fmaf(prB, __uint_as_float(hb0.y & 0xffff0000u), acc[3]);
        acc[4]  = fmaf(prB, __uint_as_float(hb0.z << 16),         acc[4]);
        acc[5]  = fmaf(prB, __uint_as_float(hb0.z & 0xffff0000u), acc[5]);
        acc[6]  = fmaf(prB, __uint_as_float(hb0.w << 16),         acc[6]);
        acc[7]  = fmaf(prB, __uint_as_float(hb0.w & 0xffff0000u), acc[7]);
        acc[8]  = fmaf(prB, __uint_as_float(hb1.x << 16),         acc[8]);
        acc[9]  = fmaf(prB, __uint_as_float(hb1.x & 0xffff0000u), acc[9]);
        acc[10] = fmaf(prB, __uint_as_float(hb1.y << 16),         acc[10]);
        acc[11] = fmaf(prB, __uint_as_float(hb1.y & 0xffff0000u), acc[11]);
        acc[12] = fmaf(prB, __uint_as_float(hb1.z << 16),         acc[12]);
        acc[13] = fmaf(prB, __uint_as_float(hb1.z & 0xffff0000u), acc[13]);
        acc[14] = fmaf(prB, __uint_as_float(hb1.w << 16),         acc[14]);
        acc[15] = fmaf(prB, __uint_as_float(hb1.w & 0xffff0000u), acc[15]);

        pA += 16; pB += 16;
        sA0 = sA1; sB0 = sB1; sA1 = sA2; sB1 = sB2;
        aA0 = aA1; aB0 = aB1;
        vA0 = vA1; vB0 = vB1; vA1 = vA2; vB1 = vB2;
    }

    den += __shfl_xor(den, 1); den += __shfl_xor(den, 2); den += __shfl_xor(den, 4);
#pragma unroll
    for (int j = 0; j < 16; ++j) {
        acc[j] += __shfl_xor(acc[j], 1);
        acc[j] += __shfl_xor(acc[j], 2);
        acc[j] += __shfl_xor(acc[j], 4);
    }
    const float inv = 1.f / (den + 1e-16f);
    float ox = acc[0], oy = acc[1];
#pragma unroll
    for (int j = 1; j < 8; ++j) {
        ox = (eL == j) ? acc[2 * j]     : ox;
        oy = (eL == j) ? acc[2 * j + 1] : oy;
    }
    const float2 b = ((const float2*)bias)[L];
    float2 o;
    o.x = fmaxf(ox * inv + b.x, 0.f);
    o.y = fmaxf(oy * inv + b.y, 0.f);
    ((float2*)out)[(size_t)n * 64 + L] = o;
}

extern "C" void kernel_launch(void* const* d_in, const int* in_sizes, int n_in,
                              void* d_out, int out_size, void* d_ws, size_t ws_size,
                              hipStream_t stream) {
    const float* x       = (const float*)d_in[0];
    const int*   ei      = (const int*)d_in[1];
    const float* W       = (const float*)d_in[2];
    const float* att_src = (const float*)d_in[3];
    const float* att_dst = (const float*)d_in[4];
    const float* bias    = (const float*)d_in[5];
    float* out = (float*)d_out;

    float* ws    = (float*)d_ws;
    unsigned short* h16 = (unsigned short*)ws;   // 12,800,000 ushorts (6.4M float slots)
    float* a_src = ws + 6400000;                 //    800,000
    float* a_dst = a_src + 800000;               //    800,000
    int* deg     = (int*)(a_dst + 800000);       //    100,000  -- memset region start
    unsigned* state = (unsigned*)(deg + 100000); //        392  -- memset region end
    int* rowptr  = (int*)(state + 392);          //    100,001
    int* posb    = rowptr + 100001;              //  1,700,000
    int* colsrc  = posb + 1700000;               //  1,700,000

    hipMemsetAsync(deg, 0, (100000 + 392) * sizeof(int), stream);

    pos_kernel<<<QUAD_NB, 256, 0, stream>>>(ei, deg, posb);
    proj_kernel<<<PROJ_NB, 256, 0, stream>>>(x, W, att_src, att_dst, h16, a_src, a_dst);
    scan_kernel<<<SCAN_NB, 256, 0, stream>>>(deg, state, rowptr);
    scatter_kernel<<<QUAD_NB, 256, 0, stream>>>(ei, rowptr, posb, colsrc);
    agg_csr_kernel<<<N_NODESC / 4, 256, 0, stream>>>(rowptr, colsrc, a_src, a_dst,
                                                     (const unsigned*)h16, bias, out);
}